// Round 12
// baseline (173.736 us; speedup 1.0000x reference)
//
#include <hip/hip_runtime.h>
#include <hip/hip_fp16.h>

#define NU_ 100000
#define NI_ 50000
#define E_  600000
#define DD  128
#define NT_ (NU_ + NI_)

// bucketed CSR build: 64-node buckets
#define BKN 64
#define NBKT ((NT_ + 63) >> 6)         // 2344 buckets
#define SBLK 8192                       // edges per scatter block
#define NSB ((E_ + SBLK - 1) / SBLK)    // 74
// item buckets: mean 64*12=768, sd ~28 -> 1024 = mean + 9.2 sigma
#define MAXE 1024

// scatter+tobf combined grid
#define TOBF_BLKS ((NT_ * DD / 8 + 511) / 512)   // 4688
#define PACK_BLKS 8

typedef short bf16x8 __attribute__((ext_vector_type(8)));
typedef float f32x4 __attribute__((ext_vector_type(4)));
typedef float f32x2 __attribute__((ext_vector_type(2)));
typedef unsigned short u16x8 __attribute__((ext_vector_type(8)));

__device__ __forceinline__ unsigned short f2bf(float x) {
  unsigned u = __float_as_uint(x);
  return (unsigned short)((u + 0x7FFFu + ((u >> 16) & 1u)) >> 16);  // RNE
}
__device__ __forceinline__ float bf2f(unsigned short h) {
  return __uint_as_float((unsigned)h << 16);
}

// bf16 A-tile swizzle: 256 B rows, XOR byte bits 4-6 with row bits 0-2
__device__ __forceinline__ int swz(int nn, int b) {
  return nn * 256 + (b ^ ((nn & 7) << 4));
}
// f32 staging swizzle: 512 B rows, same XOR
__device__ __forceinline__ int swz2(int row, int b) {
  return row * 512 + (b ^ ((row & 7) << 4));
}

// ---------------------------------------------------------------------------
// prep: per-bucket edge count (74 blk, LDS-batched global atomics) +
//       W pack (8 blk). cnt must be pre-zeroed.
// ---------------------------------------------------------------------------
__global__ __launch_bounds__(512) void prep_kernel(
    const int* __restrict__ eu, const int* __restrict__ ei,
    const float* __restrict__ W1, const float* __restrict__ W2,
    unsigned short* __restrict__ Bp, int* __restrict__ cnt) {
  __shared__ int loc[NBKT];
  int bid = blockIdx.x, tid = threadIdx.x;

  if (bid < NSB) {
    int sb = bid;
    for (int k = tid; k < NBKT; k += 512) loc[k] = 0;
    __syncthreads();
#pragma unroll
    for (int j = 0; j < SBLK / 512; j++) {
      int e = sb * SBLK + j * 512 + tid;
      if (e < E_) {
        atomicAdd(&loc[eu[e] >> 6], 1);
        atomicAdd(&loc[(NU_ + ei[e]) >> 6], 1);
      }
    }
    __syncthreads();
    for (int k = tid; k < NBKT; k += 512) {
      int c = loc[k];
      if (c) atomicAdd(&cnt[k], c);
    }
    return;
  }

  // ---- pack W1,W2 into mfma_f32_16x16x32_bf16 B-fragment order ----
  int t = (bid - NSB) * 512 + tid;  // 4096 total
  if (t >= 4096) return;
  int w = t >> 11;
  int l = t & 63;
  int kt = (t >> 6) & 3;
  int nt = (t >> 8) & 7;
  const float* W = w ? W2 : W1;
  int n = nt * 16 + (l & 15);
  int k0 = kt * 32 + (l >> 4) * 8;
  unsigned short* dst = Bp + (size_t)t * 8;
#pragma unroll
  for (int j = 0; j < 8; j++) dst[j] = f2bf(W[n * DD + k0 + j]);
}

// ---------------------------------------------------------------------------
// Single-block exclusive scan of the 2344 bucket counts -> boff, gcur.
// ---------------------------------------------------------------------------
__global__ __launch_bounds__(1024) void bscan_kernel(
    const int* __restrict__ cnt, int* __restrict__ boff, int* __restrict__ gcur) {
  __shared__ int ts[1024];
  int tid = threadIdx.x;
  int base = tid * 3;
  int v[3];
  int s = 0;
#pragma unroll
  for (int j = 0; j < 3; j++) {
    v[j] = s;
    int k = base + j;
    s += (k < NBKT) ? cnt[k] : 0;
  }
  ts[tid] = s;
  __syncthreads();
  for (int ofs = 1; ofs < 1024; ofs <<= 1) {
    int add = (tid >= ofs) ? ts[tid - ofs] : 0;
    __syncthreads();
    ts[tid] += add;
    __syncthreads();
  }
  int texcl = ts[tid] - s;
#pragma unroll
  for (int j = 0; j < 3; j++) {
    int k = base + j;
    if (k < NBKT) {
      int o = texcl + v[j];
      boff[k] = o;
      gcur[k] = o;
    }
  }
  if (tid == 1023) boff[NBKT] = ts[1023];
}

// ---------------------------------------------------------------------------
// scatter (74 blk, atomic run allocation) UNION tobf (4688 blk).
// The BW-bound f32->bf16 conversion overlaps the atomic-bound scatter.
// ---------------------------------------------------------------------------
__global__ __launch_bounds__(512) void sct_kernel(
    const int* __restrict__ eu, const int* __restrict__ ei,
    const float* __restrict__ nui, const float* __restrict__ niu,
    const float* __restrict__ fu, const float* __restrict__ fi,
    unsigned short* __restrict__ fub, unsigned short* __restrict__ fib,
    int* __restrict__ gcur, int2* __restrict__ binned) {
  __shared__ int loc[NBKT];
  int bid = blockIdx.x, tid = threadIdx.x;

  if (bid < NSB) {
    int sb = bid;
    for (int k = tid; k < NBKT; k += 512) loc[k] = 0;
    __syncthreads();
    // pass 1: local histogram
#pragma unroll
    for (int j = 0; j < SBLK / 512; j++) {
      int e = sb * SBLK + j * 512 + tid;
      if (e < E_) {
        atomicAdd(&loc[eu[e] >> 6], 1);
        atomicAdd(&loc[(NU_ + ei[e]) >> 6], 1);
      }
    }
    __syncthreads();
    // allocate contiguous runs per touched bucket
    for (int k = tid; k < NBKT; k += 512) {
      int c = loc[k];
      loc[k] = c ? atomicAdd(&gcur[k], c) : 0;
    }
    __syncthreads();
    // pass 2: place entries (edges re-read from L2)
#pragma unroll
    for (int j = 0; j < SBLK / 512; j++) {
      int e = sb * SBLK + j * 512 + tid;
      if (e < E_) {
        int u = eu[e], i = ei[e];
        int gi = NU_ + i;
        int s1 = atomicAdd(&loc[u >> 6], 1);
        binned[s1] = make_int2(((u & 63) << 20) | i, __float_as_int(niu[e]));
        int s2 = atomicAdd(&loc[gi >> 6], 1);
        binned[s2] = make_int2(((gi & 63) << 20) | u, __float_as_int(nui[e]));
      }
    }
    return;
  }

  // ---- f32 -> bf16 feature tables ----
  int t = (bid - NSB) * 512 + tid;
  int nu8 = NU_ * DD / 8;
  int nt8 = NT_ * DD / 8;
  if (t >= nt8) return;
  const float* src;
  unsigned short* dst;
  int k;
  if (t < nu8) { src = fu; dst = fub; k = t; }
  else { src = fi; dst = fib; k = t - nu8; }
  const float4 v0 = reinterpret_cast<const float4*>(src)[k * 2];
  const float4 v1 = reinterpret_cast<const float4*>(src)[k * 2 + 1];
  u16x8 o;
  o[0] = f2bf(v0.x); o[1] = f2bf(v0.y); o[2] = f2bf(v0.z); o[3] = f2bf(v0.w);
  o[4] = f2bf(v1.x); o[5] = f2bf(v1.y); o[6] = f2bf(v1.z); o[7] = f2bf(v1.w);
  reinterpret_cast<u16x8*>(dst)[k] = o;
}

// ---------------------------------------------------------------------------
// Fused gather + MFMA GEMM + epilogue, 64-node buckets (4 blocks/CU).
// Gather inner loop: packed-f32 pairs (v_pk_fma path) + 2-deep entry unroll.
// ---------------------------------------------------------------------------
__global__ __launch_bounds__(512, 8) void fused_kernel(
    const unsigned short* __restrict__ fub, const unsigned short* __restrict__ fib,
    const float* __restrict__ nu, const float* __restrict__ ni,
    const int* __restrict__ boff, const int2* __restrict__ binned,
    const unsigned short* __restrict__ Bp,
    const float* __restrict__ b1, const float* __restrict__ b2,
    float* __restrict__ out) {
  __shared__ __align__(16) unsigned short XM[2 * BKN * 128];  // 32 KB
  __shared__ int eidx[MAXE];                                  // 4 KB
  __shared__ unsigned short ew[MAXE];                         // 2 KB
  __shared__ int csrtmp[128];   // ncnt|ncur; later ssx[64][2]
  __shared__ int nstart[BKN + 1];

  unsigned short* Xs = XM;
  unsigned short* Ms = XM + BKN * 128;
  int* ncnt = csrtmp;
  int* ncur = csrtmp + 64;

  int bkt = blockIdx.x, tid = threadIdx.x;
  int bs = boff[bkt];
  int be = boff[bkt + 1];
  int cnt = be - bs;
  if (cnt > MAXE) cnt = MAXE;  // 9-sigma safety net

  // ---- per-node CSR in LDS; entries register-carried (cnt <= 1024) ----
  if (tid < BKN) ncnt[tid] = 0;
  __syncthreads();
  int2 e0, e1;
  bool h0 = tid < cnt, h1 = tid + 512 < cnt;
  if (h0) {
    e0 = binned[bs + tid];
    atomicAdd(&ncnt[(e0.x >> 20) & 63], 1);
  }
  if (h1) {
    e1 = binned[bs + tid + 512];
    atomicAdd(&ncnt[(e1.x >> 20) & 63], 1);
  }
  __syncthreads();

  if (tid < BKN) {  // single-wave shfl scan of 64 counters
    int a = ncnt[tid];
    int incl = a;
#pragma unroll
    for (int ofs = 1; ofs < 64; ofs <<= 1) {
      int t = __shfl_up(incl, ofs);
      if (tid >= ofs) incl += t;
    }
    if (tid == 0) nstart[0] = 0;
    nstart[tid + 1] = incl;
    ncur[tid] = incl - a;
  }
  __syncthreads();

  if (h0) {
    int slot = atomicAdd(&ncur[(e0.x >> 20) & 63], 1);
    eidx[slot] = e0.x & 0xFFFFF;
    ew[slot] = __half_as_ushort(__float2half(__int_as_float(e0.y)));
  }
  if (h1) {
    int slot = atomicAdd(&ncur[(e1.x >> 20) & 63], 1);
    eidx[slot] = e1.x & 0xFFFFF;
    ew[slot] = __half_as_ushort(__float2half(__int_as_float(e1.y)));
  }
  __syncthreads();

  int wid = tid >> 6, lane = tid & 63;
  int q = lane >> 4, sub = lane & 15;

  // ---- gather phase: 8 nodes/wave, quarter-wave per neighbor, 2-deep ----
  for (int nn = 0; nn < 8; nn++) {
    int gl = wid * 8 + nn;
    int g = bkt * BKN + gl;
    if (g >= NT_) break;
    bool isU = g < NU_;
    const unsigned short* nbF = isU ? fib : fub;
    const float* nbS = isU ? ni : nu;
    int cs = nstart[gl], ce = nstart[gl + 1];

    f32x2 pA[4], pM[4];
#pragma unroll
    for (int k = 0; k < 4; k++) {
      pA[k] = (f32x2){0.f, 0.f};
      pM[k] = (f32x2){0.f, 0.f};
    }

#define GPAIRS(dd, wv, sv)                                                   \
    {                                                                        \
      f32x2 r0, r1, r2, r3;                                                  \
      r0.x = __uint_as_float((dd).x << 16);                                  \
      r0.y = __uint_as_float((dd).x & 0xFFFF0000u);                          \
      r1.x = __uint_as_float((dd).y << 16);                                  \
      r1.y = __uint_as_float((dd).y & 0xFFFF0000u);                          \
      r2.x = __uint_as_float((dd).z << 16);                                  \
      r2.y = __uint_as_float((dd).z & 0xFFFF0000u);                          \
      r3.x = __uint_as_float((dd).w << 16);                                  \
      r3.y = __uint_as_float((dd).w & 0xFFFF0000u);                          \
      pA[0] += r0 * (wv); pM[0] += r0 * (sv);                                \
      pA[1] += r1 * (wv); pM[1] += r1 * (sv);                                \
      pA[2] += r2 * (wv); pM[2] += r2 * (sv);                                \
      pA[3] += r3 * (wv); pM[3] += r3 * (sv);                                \
    }

    int j = cs + q;
    for (; j + 4 < ce; j += 8) {  // two independent rows in flight
      int i0 = eidx[j], i1 = eidx[j + 4];
      float w0 = __half2float(__ushort_as_half(ew[j]));
      float w1 = __half2float(__ushort_as_half(ew[j + 4]));
      float s0 = nbS[i0], s1 = nbS[i1];
      uint4 d0 = *reinterpret_cast<const uint4*>(nbF + (size_t)i0 * DD + sub * 8);
      uint4 d1 = *reinterpret_cast<const uint4*>(nbF + (size_t)i1 * DD + sub * 8);
      f32x2 wv0 = {w0, w0}, sv0 = {s0, s0};
      f32x2 wv1 = {w1, w1}, sv1 = {s1, s1};
      GPAIRS(d0, wv0, sv0);
      GPAIRS(d1, wv1, sv1);
    }
    if (j < ce) {
      int i0 = eidx[j];
      float w0 = __half2float(__ushort_as_half(ew[j]));
      float s0 = nbS[i0];
      uint4 d0 = *reinterpret_cast<const uint4*>(nbF + (size_t)i0 * DD + sub * 8);
      f32x2 wv0 = {w0, w0}, sv0 = {s0, s0};
      GPAIRS(d0, wv0, sv0);
    }
#undef GPAIRS

    // cross-quarter reduce (pairs reduced componentwise)
#pragma unroll
    for (int k = 0; k < 4; k++) {
      pA[k].x += __shfl_xor(pA[k].x, 16); pA[k].x += __shfl_xor(pA[k].x, 32);
      pA[k].y += __shfl_xor(pA[k].y, 16); pA[k].y += __shfl_xor(pA[k].y, 32);
      pM[k].x += __shfl_xor(pM[k].x, 16); pM[k].x += __shfl_xor(pM[k].x, 32);
      pM[k].y += __shfl_xor(pM[k].y, 16); pM[k].y += __shfl_xor(pM[k].y, 32);
    }

    int lrow = isU ? g : g - NU_;
    if (q < 2) {
      const unsigned short* ownp = (isU ? fub : fib) + (size_t)lrow * DD + sub * 8;
      u16x8 fo = *reinterpret_cast<const u16x8*>(ownp);
      u16x8 o;
      if (q == 0) {
#pragma unroll
        for (int k = 0; k < 4; k++) {
          o[2 * k] = f2bf(bf2f((unsigned short)fo[2 * k]) + pA[k].x);
          o[2 * k + 1] = f2bf(bf2f((unsigned short)fo[2 * k + 1]) + pA[k].y);
        }
        *reinterpret_cast<u16x8*>((char*)Xs + swz(gl, sub * 16)) = o;
      } else {
        float so = isU ? nu[lrow] : ni[lrow];
#pragma unroll
        for (int k = 0; k < 4; k++) {
          o[2 * k] = f2bf(bf2f((unsigned short)fo[2 * k]) * so * pM[k].x);
          o[2 * k + 1] = f2bf(bf2f((unsigned short)fo[2 * k + 1]) * so * pM[k].y);
        }
        *reinterpret_cast<u16x8*>((char*)Ms + swz(gl, sub * 16)) = o;
      }
    }
  }
  __syncthreads();

  // ---- MFMA phase: tile t = wid>>1 (rows t*16..+15), cols (wid&1)*64..+63 ----
  int t = wid >> 1, colHalf = wid & 1;
  int gt0 = bkt * BKN + t * 16;
  bool active = gt0 < NT_;  // tail bucket tiles are 16-aligned

  int lm = lane & 15, lh = lane >> 4;
  float h[4][4];
  float inv4[4];
  float (*ssx)[2] = (float(*)[2])csrtmp;  // overlays ncnt/ncur (dead now)

  if (active) {
    f32x4 acc[4];
#pragma unroll
    for (int nt = 0; nt < 4; nt++) acc[nt] = (f32x4){0.f, 0.f, 0.f, 0.f};

#pragma unroll
    for (int kt = 0; kt < 4; kt++) {  // kt-outer keeps VGPR low
      int b = kt * 64 + lh * 16;
      bf16x8 a1 = *reinterpret_cast<const bf16x8*>((char*)Xs + swz(t * 16 + lm, b));
      bf16x8 a2 = *reinterpret_cast<const bf16x8*>((char*)Ms + swz(t * 16 + lm, b));
#pragma unroll
      for (int nt = 0; nt < 4; nt++) {
        int ntp = colHalf * 4 + nt;
        bf16x8 bf1 = *reinterpret_cast<const bf16x8*>(Bp + ((size_t)((0 * 8 + ntp) * 4 + kt) * 64 + lane) * 8);
        acc[nt] = __builtin_amdgcn_mfma_f32_16x16x32_bf16(a1, bf1, acc[nt], 0, 0, 0);
        bf16x8 bf2 = *reinterpret_cast<const bf16x8*>(Bp + ((size_t)((1 * 8 + ntp) * 4 + kt) * 64 + lane) * 8);
        acc[nt] = __builtin_amdgcn_mfma_f32_16x16x32_bf16(a2, bf2, acc[nt], 0, 0, 0);
      }
    }

    // bias -> leaky relu -> partial row sum-of-squares (this col half)
    float ss[4] = {0.f, 0.f, 0.f, 0.f};
#pragma unroll
    for (int nt = 0; nt < 4; nt++) {
      int ntp = colHalf * 4 + nt;
      float bb = b1[ntp * 16 + lm] + b2[ntp * 16 + lm];
#pragma unroll
      for (int r = 0; r < 4; r++) {
        float v = acc[nt][r] + bb;
        v = (v > 0.f) ? v : 0.2f * v;
        h[nt][r] = v;
        ss[r] += v * v;
      }
    }
#pragma unroll
    for (int r = 0; r < 4; r++) {
#pragma unroll
      for (int m = 1; m < 16; m <<= 1) ss[r] += __shfl_xor(ss[r], m);
    }
    if (lm == 0) {
#pragma unroll
      for (int r = 0; r < 4; r++) ssx[t * 16 + lh * 4 + r][colHalf] = ss[r];
    }
  }
  __syncthreads();  // ssx ready; all XM fragment reads complete

  if (active) {
#pragma unroll
    for (int r = 0; r < 4; r++) {
      int row = t * 16 + lh * 4 + r;
      float tot = ssx[row][0] + ssx[row][1];
      inv4[r] = 1.0f / fmaxf(sqrtf(tot), 1e-12f);
    }
    // stage normalized f32 rows in (now-free) XM
    float* stg = reinterpret_cast<float*>(XM);  // [64 rows][512 B]
#pragma unroll
    for (int nt = 0; nt < 4; nt++) {
      int ntp = colHalf * 4 + nt;
#pragma unroll
      for (int r = 0; r < 4; r++) {
        int row = t * 16 + lh * 4 + r;
        *reinterpret_cast<float*>((char*)stg + swz2(row, ntp * 64 + lm * 4)) =
            h[nt][r] * inv4[r];
      }
    }
  }
  __syncthreads();

  // ---- contiguous 32 KB block write ----
  float* stg = reinterpret_cast<float*>(XM);
  int maxrow = NT_ - bkt * BKN;  // <64 only for the tail bucket
  float* ob = out + (size_t)bkt * BKN * DD;
#pragma unroll
  for (int k = 0; k < 4; k++) {
    int c = k * 512 + tid;  // 16B chunk id, 2048 total
    int row = c >> 5;
    if (row < maxrow) {
      f32x4 v = *reinterpret_cast<const f32x4*>((char*)stg + swz2(row, (c & 31) * 16));
      *reinterpret_cast<f32x4*>(ob + (size_t)c * 4) = v;
    }
  }
}

// ---------------------------------------------------------------------------
extern "C" void kernel_launch(void* const* d_in, const int* in_sizes, int n_in,
                              void* d_out, int out_size, void* d_ws, size_t ws_size,
                              hipStream_t stream) {
  const float* fu  = (const float*)d_in[0];
  const float* fi  = (const float*)d_in[1];
  const float* nu  = (const float*)d_in[2];
  const float* ni  = (const float*)d_in[3];
  const float* nui = (const float*)d_in[4];
  const float* niu = (const float*)d_in[5];
  const float* W1  = (const float*)d_in[6];
  const float* b1  = (const float*)d_in[7];
  const float* W2  = (const float*)d_in[8];
  const float* b2  = (const float*)d_in[9];
  const int* eu    = (const int*)d_in[10];
  const int* ei    = (const int*)d_in[11];
  float* out = (float*)d_out;
  char* ws = (char*)d_ws;

  size_t off_b = 0;
  auto alloc = [&](size_t bytes) {
    char* p = ws + off_b;
    off_b += (bytes + 255) & ~(size_t)255;
    return p;
  };
  unsigned short* fub = (unsigned short*)alloc((size_t)NU_ * DD * 2);
  unsigned short* fib = (unsigned short*)alloc((size_t)NI_ * DD * 2);
  unsigned short* Bp  = (unsigned short*)alloc(4096 * 8 * 2);
  int* cnt  = (int*)alloc(NBKT * 4);
  int* boff = (int*)alloc((NBKT + 1) * 4);
  int* gcur = (int*)alloc(NBKT * 4);
  int2* binned = (int2*)alloc((size_t)2 * E_ * 8);

  hipMemsetAsync(cnt, 0, NBKT * sizeof(int), stream);

  prep_kernel<<<NSB + PACK_BLKS, 512, 0, stream>>>(eu, ei, W1, W2, Bp, cnt);
  bscan_kernel<<<1, 1024, 0, stream>>>(cnt, boff, gcur);
  sct_kernel<<<NSB + TOBF_BLKS, 512, 0, stream>>>(
      eu, ei, nui, niu, fu, fi, fub, fib, gcur, binned);

  fused_kernel<<<NBKT, 512, 0, stream>>>(
      fub, fib, nu, ni, boff, binned, Bp, b1, b2, out);
}